// Round 9
// baseline (588.821 us; speedup 1.0000x reference)
//
#include <hip/hip_runtime.h>
#include <hip/hip_fp16.h>
#include <math.h>

#define N_NODES 200000
#define N_EDGES 6400000
#define T 6
#define M 10

// CSR build: 1024-node buckets (dst>>10), chunked counting sort.
// 1024-node buckets give ~668 B write runs in passC (vs 168 B at 256-node),
// so L2 fills whole lines before eviction (R8: 256-node buckets cost 4.4x
// write amplification).
#define BSH   10             // bucket shift
#define NBKT  196            // ceil(200000/1024)
#define NBLK  196            // ceil(6400000/32768) edge chunks
#define CH    32768          // edges per chunk
#define GHLEN (NBKT * NBLK)  // 38416

#define SBLOCKS 38           // ceil(GHLEN/1024)

typedef __attribute__((ext_vector_type(2))) float vf2;
typedef __attribute__((ext_vector_type(4))) unsigned int u32x4;

// ---------------------------------------------------------------------------
// convert x_member [N,6] fp32 -> xh [N,8] fp16 (zero-padded), 16 B rows.
// ---------------------------------------------------------------------------
__global__ __launch_bounds__(256) void convert_kernel(
    const float* __restrict__ x, __half* __restrict__ xh)
{
    int i = blockIdx.x * 256 + threadIdx.x;
    if (i >= N_NODES) return;
    const vf2* p = (const vf2*)(x + (size_t)i * 6);   // rows 24B -> 8B aligned
    vf2 a = __builtin_nontemporal_load(p);
    vf2 b = __builtin_nontemporal_load(p + 1);
    vf2 c = __builtin_nontemporal_load(p + 2);
    union { __half2 h[4]; u32x4 q; } u;
    u.h[0] = __floats2half2_rn(a.x, a.y);
    u.h[1] = __floats2half2_rn(b.x, b.y);
    u.h[2] = __floats2half2_rn(c.x, c.y);
    u.h[3] = __floats2half2_rn(0.f, 0.f);
    __builtin_nontemporal_store(u.q, (u32x4*)(xh + (size_t)i * 8));
}

// ---------------------------------------------------------------------------
// Pass A: per-chunk bucket histogram -> gh[bucket*NBLK + chunk]
// ---------------------------------------------------------------------------
__global__ __launch_bounds__(512) void passA_kernel(
    const int* __restrict__ dst, int* __restrict__ gh)
{
    __shared__ int lh[NBKT];
    int g = blockIdx.x;
    if (threadIdx.x < NBKT) lh[threadIdx.x] = 0;
    __syncthreads();
    int base = g * CH;
    int end  = base + CH; if (end > N_EDGES) end = N_EDGES;
    for (int e = base + threadIdx.x; e < end; e += 512)
        atomicAdd(&lh[__builtin_nontemporal_load(dst + e) >> BSH], 1);
    __syncthreads();
    if (threadIdx.x < NBKT) gh[threadIdx.x * NBLK + g] = lh[threadIdx.x];
}

// ---------------------------------------------------------------------------
// Hierarchical exclusive scan of gh[GHLEN]
// ---------------------------------------------------------------------------
__global__ __launch_bounds__(1024) void scan1_kernel(
    int* __restrict__ gh, int* __restrict__ bsum)
{
    __shared__ int sbuf[1024];
    int tid = threadIdx.x;
    int t   = blockIdx.x * 1024 + tid;
    int v   = (t < GHLEN) ? gh[t] : 0;
    sbuf[tid] = v;
    __syncthreads();
    for (int d = 1; d < 1024; d <<= 1) {
        int u = (tid >= d) ? sbuf[tid - d] : 0;
        __syncthreads();
        sbuf[tid] += u;
        __syncthreads();
    }
    if (t < GHLEN) gh[t] = sbuf[tid] - v;           // local exclusive
    if (tid == 1023) bsum[blockIdx.x] = sbuf[1023]; // block total
}

__global__ __launch_bounds__(256) void scan2_kernel(int* __restrict__ bsum)
{
    __shared__ int sbuf[256];
    int tid = threadIdx.x;
    int v = (tid < SBLOCKS) ? bsum[tid] : 0;
    sbuf[tid] = v;
    __syncthreads();
    for (int d = 1; d < 256; d <<= 1) {
        int u = (tid >= d) ? sbuf[tid - d] : 0;
        __syncthreads();
        sbuf[tid] += u;
        __syncthreads();
    }
    if (tid < SBLOCKS) bsum[tid] = sbuf[tid] - v;   // exclusive
}

__global__ __launch_bounds__(1024) void scan3_kernel(
    int* __restrict__ gh, const int* __restrict__ bsum)
{
    int t = blockIdx.x * 1024 + threadIdx.x;
    if (t < GHLEN) gh[t] += bsum[blockIdx.x];
}

// ---------------------------------------------------------------------------
// Pass C: place edges into bucket-grouped ebuf via LDS cursors.
// ebuf[pos] = (src<<10) | (dst & 1023)  (src<2^18, fits 28 bits).
// Runs are ~668 B -> L2 coalesces the scattered stores (normal stores).
// ---------------------------------------------------------------------------
__global__ __launch_bounds__(512) void passC_kernel(
    const int* __restrict__ src, const int* __restrict__ dst,
    const int* __restrict__ gh, int* __restrict__ ebuf)
{
    __shared__ int lcur[NBKT];
    int g = blockIdx.x;
    if (threadIdx.x < NBKT) lcur[threadIdx.x] = gh[threadIdx.x * NBLK + g];
    __syncthreads();
    int base = g * CH;
    int end  = base + CH; if (end > N_EDGES) end = N_EDGES;
    for (int e = base + threadIdx.x; e < end; e += 512) {
        int s = __builtin_nontemporal_load(src + e);
        int d = __builtin_nontemporal_load(dst + e);
        int p = atomicAdd(&lcur[d >> BSH], 1);    // LDS atomic
        ebuf[p] = (s << BSH) | (d & 1023);
    }
}

// ---------------------------------------------------------------------------
// Pass D: per-bucket counting sort, 1024 nodes/bucket, 1024 threads/block.
// No LDS staging (bucket ~130 KB > LDS): two streaming passes over the
// bucket's ebuf range. col is a SEPARATE buffer (in-place impossible without
// staging). Scatter-writes are confined to a ~130 KB window -> L2 coalesces.
// off[node] = bucket_base + inclusive_prefix (round kernels use
// start = off[i-1], end = off[i]; bucket boundaries line up exactly).
// ---------------------------------------------------------------------------
__global__ __launch_bounds__(1024) void passD_kernel(
    const int* __restrict__ gh, const int* __restrict__ ebuf,
    int* __restrict__ col, int* __restrict__ off)
{
    __shared__ int hist[1024];
    __shared__ int incl[1024];
    int b = blockIdx.x;
    int ebase = gh[b * NBLK];
    int eend  = (b == NBKT - 1) ? N_EDGES : gh[(b + 1) * NBLK];
    int t = threadIdx.x;

    hist[t] = 0;
    __syncthreads();
    for (int k = ebase + t; k < eend; k += 1024)
        atomicAdd(&hist[__builtin_nontemporal_load(ebuf + k) & 1023], 1);
    __syncthreads();
    int h = hist[t];
    incl[t] = h;
    __syncthreads();
    for (int d = 1; d < 1024; d <<= 1) {
        int v = (t >= d) ? incl[t - d] : 0;
        __syncthreads();
        incl[t] += v;
        __syncthreads();
    }
    int node = (b << BSH) + t;
    if (node < N_NODES) off[node] = ebase + incl[t];
    hist[t] = incl[t] - h;                        // exclusive cursor
    __syncthreads();
    for (int k = ebase + t; k < eend; k += 1024) {
        int e = __builtin_nontemporal_load(ebuf + k);   // LLC-warm re-read
        int p = atomicAdd(&hist[e & 1023], 1);    // LDS atomic
        col[ebase + p] = e >> BSH;                // normal store (L2 coalesces)
    }
}

// ---------------------------------------------------------------------------
// round: v = in[i] + sum_{j in CSR(i)} in[col[j]]; rout[i] = sigmoid(v @ H)
// stored fp8 e4m3 (16 B rows -> 3.2 MB gather table).
// col/off reads NT (stream, don't evict the gather table from L2);
// rout store NT (coalesced write-once).
// ---------------------------------------------------------------------------
template<int TD, bool FP8IN>
__device__ inline void accum_row(u32x4 q, float* v)
{
    if (FP8IN) {
        vf2 f0 = __builtin_amdgcn_cvt_pk_f32_fp8(q.x, false);
        vf2 f1 = __builtin_amdgcn_cvt_pk_f32_fp8(q.x, true);
        vf2 f2 = __builtin_amdgcn_cvt_pk_f32_fp8(q.y, false);
        vf2 f3 = __builtin_amdgcn_cvt_pk_f32_fp8(q.y, true);
        vf2 f4 = __builtin_amdgcn_cvt_pk_f32_fp8(q.z, false);
        v[0] += f0.x; v[1] += f0.y; v[2] += f1.x; v[3] += f1.y;
        v[4] += f2.x; v[5] += f2.y; v[6] += f3.x; v[7] += f3.y;
        v[8] += f4.x; v[9] += f4.y;
    } else {
        union { u32x4 q; __half2 h[8]; } u; u.q = q;
#pragma unroll
        for (int k = 0; k < TD / 2; ++k) {
            float2 f = __half22float2(u.h[k]);
            v[2 * k] += f.x; v[2 * k + 1] += f.y;
        }
    }
}

template<int TD, bool FP8IN>
__global__ __launch_bounds__(256) void round_kernel(
    const u32x4* __restrict__ in,      // [N] 16 B rows (fp16x8 or fp8x16)
    const int*   __restrict__ off,
    const int*   __restrict__ col,
    u32x4*       __restrict__ rout,    // [N] 16 B fp8 rows
    const float* __restrict__ H,       // [TD, M]
    const float* __restrict__ Wsc, int widx,
    float*       __restrict__ facc)
{
    int i = blockIdx.x * 256 + threadIdx.x;
    float w = Wsc[widx];
    float sm[M];

    if (i < N_NODES) {
        float v[TD];
#pragma unroll
        for (int t = 0; t < TD; ++t) v[t] = 0.0f;
        accum_row<TD, FP8IN>(in[i], v);
        int start = (i == 0) ? 0 : __builtin_nontemporal_load(off + i - 1);
        int end   = __builtin_nontemporal_load(off + i);

        int j = start;
        for (; j + 4 <= end; j += 4) {           // 4 outstanding gathers/lane
            int s0 = __builtin_nontemporal_load(col + j);
            int s1 = __builtin_nontemporal_load(col + j + 1);
            int s2 = __builtin_nontemporal_load(col + j + 2);
            int s3 = __builtin_nontemporal_load(col + j + 3);
            u32x4 q0 = in[s0], q1 = in[s1], q2 = in[s2], q3 = in[s3];
            accum_row<TD, FP8IN>(q0, v);
            accum_row<TD, FP8IN>(q1, v);
            accum_row<TD, FP8IN>(q2, v);
            accum_row<TD, FP8IN>(q3, v);
        }
        for (; j < end; ++j)
            accum_row<TD, FP8IN>(in[__builtin_nontemporal_load(col + j)], v);

        float z[M];
#pragma unroll
        for (int m = 0; m < M; ++m) {
            float acc = 0.0f;
#pragma unroll
            for (int t = 0; t < TD; ++t) acc += v[t] * H[t * M + m];
            z[m] = acc;
        }
        float rr[M];
        float ssum = 0.0f;
#pragma unroll
        for (int m = 0; m < M; ++m) {
            rr[m] = 1.0f / (1.0f + __expf(-z[m]));
            sm[m] = __expf(rr[m] * w);            // rr*w in (0,0.2): no max shift
            ssum += sm[m];
        }
        {
            int d0 = __builtin_amdgcn_cvt_pk_fp8_f32(rr[0], rr[1], 0, false);
            d0     = __builtin_amdgcn_cvt_pk_fp8_f32(rr[2], rr[3], d0, true);
            int d1 = __builtin_amdgcn_cvt_pk_fp8_f32(rr[4], rr[5], 0, false);
            d1     = __builtin_amdgcn_cvt_pk_fp8_f32(rr[6], rr[7], d1, true);
            int d2 = __builtin_amdgcn_cvt_pk_fp8_f32(rr[8], rr[9], 0, false);
            u32x4 o = { (unsigned)d0, (unsigned)d1, (unsigned)d2, 0u };
            __builtin_nontemporal_store(o, rout + i);
        }
        float inv = 1.0f / ssum;
#pragma unroll
        for (int m = 0; m < M; ++m) sm[m] *= inv;
    } else {
#pragma unroll
        for (int m = 0; m < M; ++m) sm[m] = 0.0f;
    }

    // wave-64 shuffle reduction of the 10 softmax sums
#pragma unroll
    for (int m = 0; m < M; ++m) {
        float x = sm[m];
#pragma unroll
        for (int o = 32; o > 0; o >>= 1) x += __shfl_down(x, o);
        sm[m] = x;
    }
    __shared__ float ls[4][M];
    int lane = threadIdx.x & 63;
    int wv   = threadIdx.x >> 6;
    if (lane == 0) {
#pragma unroll
        for (int m = 0; m < M; ++m) ls[wv][m] = sm[m];
    }
    __syncthreads();
    if (threadIdx.x < M) {
        float a = ls[0][threadIdx.x] + ls[1][threadIdx.x]
                + ls[2][threadIdx.x] + ls[3][threadIdx.x];
        atomicAdd(&facc[threadIdx.x], a);
    }
}

// ---------------------------------------------------------------------------
// final head: out[3] = concat(f[10], x_group@Wg[4]) @ Wm
// ---------------------------------------------------------------------------
__global__ void final_kernel(const float* __restrict__ facc,
                             const float* __restrict__ xg,
                             const float* __restrict__ Wg,
                             const float* __restrict__ Wm,
                             float* __restrict__ out)
{
    if (threadIdx.x == 0 && blockIdx.x == 0) {
        float go[4];
        for (int g = 0; g < 4; ++g) {
            float a = 0.0f;
            for (int i = 0; i < 14; ++i) a += xg[i] * Wg[i * 4 + g];
            go[g] = a;
        }
        for (int j = 0; j < 3; ++j) {
            float o = 0.0f;
            for (int k = 0; k < M; ++k) o += facc[k] * Wm[k * 3 + j];
            for (int g = 0; g < 4; ++g)  o += go[g] * Wm[(M + g) * 3 + j];
            out[j] = o;
        }
    }
}

extern "C" void kernel_launch(void* const* d_in, const int* in_sizes, int n_in,
                              void* d_out, int out_size, void* d_ws, size_t ws_size,
                              hipStream_t stream)
{
    const float* x_member = (const float*)d_in[0];
    const float* x_group  = (const float*)d_in[1];
    const int*   edge_src = (const int*)  d_in[2];
    const int*   edge_dst = (const int*)  d_in[3];
    const float* H0       = (const float*)d_in[4];
    const float* Hs       = (const float*)d_in[5];
    const float* Wsc      = (const float*)d_in[6];
    const float* Wg       = (const float*)d_in[7];
    const float* Wm       = (const float*)d_in[8];
    float* out = (float*)d_out;

    // workspace layout — 61.6 MB:
    //   ebuf : 25,600,000 B   bucket-grouped packed edges
    //   col  : 25,600,000 B   node-sorted src (separate: unstaged passD)
    //   off  :    800,000 B
    //   xh   :  3,200,000 B   [N] fp16x8, 16 B rows
    //   r0b  :  3,200,000 B   [N] fp8x16, 16 B rows
    //   r1b  :  3,200,000 B   [N] fp8x16 (gh[GHLEN]+bsum alias its head:
    //          dead after passD; r1b first written in round 1)
    //   facc :         64 B
    char* w = (char*)d_ws;
    int*    ebuf = (int*)w;
    int*    col  = (int*)(w + 25600000);
    int*    off  = (int*)(w + 51200000);
    __half* xh   = (__half*)(w + 52000000);
    u32x4*  r0b  = (u32x4*)(w + 55200000);
    u32x4*  r1b  = (u32x4*)(w + 58400000);
    int*    gh   = (int*)(w + 58400000);          // aliases r1b
    int*    bsum = gh + GHLEN;                    // also in r1b region
    float*  facc = (float*)(w + 61600000);

    (void)hipMemsetAsync(facc, 0, 64, stream);

    const int nblocks = (N_NODES + 255) / 256;    // 782

    convert_kernel<<<nblocks, 256, 0, stream>>>(x_member, xh);
    passA_kernel<<<NBLK, 512, 0, stream>>>(edge_dst, gh);
    scan1_kernel<<<SBLOCKS, 1024, 0, stream>>>(gh, bsum);
    scan2_kernel<<<1, 256, 0, stream>>>(bsum);
    scan3_kernel<<<SBLOCKS, 1024, 0, stream>>>(gh, bsum);
    passC_kernel<<<NBLK, 512, 0, stream>>>(edge_src, edge_dst, gh, ebuf);
    passD_kernel<<<NBKT, 1024, 0, stream>>>(gh, ebuf, col, off);

    round_kernel<T, false><<<nblocks, 256, 0, stream>>>((const u32x4*)xh, off, col, r0b, H0,             Wsc, 0, facc);
    round_kernel<M, true ><<<nblocks, 256, 0, stream>>>(r0b,              off, col, r1b, Hs + 0 * M * M, Wsc, 1, facc);
    round_kernel<M, true ><<<nblocks, 256, 0, stream>>>(r1b,              off, col, r0b, Hs + 1 * M * M, Wsc, 2, facc);
    round_kernel<M, true ><<<nblocks, 256, 0, stream>>>(r0b,              off, col, r1b, Hs + 2 * M * M, Wsc, 3, facc);

    final_kernel<<<1, 64, 0, stream>>>(facc, x_group, Wg, Wm, out);
}